// Round 6
// baseline (174.317 us; speedup 1.0000x reference)
//
#include <hip/hip_runtime.h>

// SNN classifier: T=500, B=256, 96 -> 64 -> 80, leaky (subtract reset).
// f32 BLAS-order arithmetic replicated exactly (single-accumulator
// k-ascending __fmaf_rn chains; fixed leaky op-sequence) -> outputs
// bitwise-identical to the passing round-2..5 kernels.
//
// Round-6: round-5's K1 (120us) put the STREAMED operand (x, cold in
// L2/HBM, ~900cyc) on the scalar-load path where SGPR space caps prefetch
// depth (~24 dwordx4) -> latency-stall-bound (VALUBusy 39%). K3 shows the
// right role split: uniform operand = small cache-resident weight matrix
// (short latency), per-lane VMEM operand = the stream (VGPR-double-buffered,
// deep prefetch). Round-6 K1 adopts it:
//   lane = b (64 consecutive batch elems of one t). x row = per-lane VMEM
//   stream, 16-float chunks, explicit A/B double-buffer (static indexing).
//   W1 = wave-uniform s_load (24KB, all-block reuse -> scalar-cache hot).
//   Two h-halves of acc[32]; k-chain order per output unchanged.
// K2/K3/K4 untouched (single-variable change).

#define T_STEPS 500
#define BATCH   256
#define N_IN    96
#define N_HID   64
#define N_OUT   80
#define CH      50   // chunk size in K2/K4 (500 = 10*50)

// ---------------- K1: cur1 = x @ W1 + b1 ----------------
// grid 500*4, block 64. Block = (t, 64-wide b-group). Lane = b.
__global__ __launch_bounds__(64) void k1_cur1(
    const float* __restrict__ x,   // (T,B,96)
    const float* __restrict__ W1,  // (96,64)
    const float* __restrict__ b1,  // (64)
    float* __restrict__ cur1)      // (T,B,64) region inside outs
{
    const int t    = blockIdx.x >> 2;
    const int b    = ((blockIdx.x & 3) << 6) + threadIdx.x;
    const float* __restrict__ xr  = x    + ((size_t)t * BATCH + b) * N_IN;
    float*       __restrict__ dst = cur1 + ((size_t)t * BATCH + b) * N_HID;

#define LOADX(buf, kc)                                                        \
    {                                                                         \
        const float4* __restrict__ p =                                        \
            reinterpret_cast<const float4*>(xr + (kc) * 16);                  \
        float4 v0 = p[0], v1 = p[1], v2 = p[2], v3 = p[3];                    \
        buf[0]=v0.x; buf[1]=v0.y; buf[2]=v0.z; buf[3]=v0.w;                   \
        buf[4]=v1.x; buf[5]=v1.y; buf[6]=v1.z; buf[7]=v1.w;                   \
        buf[8]=v2.x; buf[9]=v2.y; buf[10]=v2.z; buf[11]=v2.w;                 \
        buf[12]=v3.x; buf[13]=v3.y; buf[14]=v3.z; buf[15]=v3.w;               \
    }

#define COMPUTE(buf, kc)                                                      \
    _Pragma("unroll")                                                         \
    for (int j = 0; j < 16; ++j) {                                            \
        const int k = (kc) * 16 + j;                                          \
        const float4* __restrict__ wr =                                       \
            reinterpret_cast<const float4*>(W1 + (size_t)k * N_HID + o0);     \
        const float xv = buf[j];                                              \
        _Pragma("unroll")                                                     \
        for (int o4 = 0; o4 < 8; ++o4) {                                      \
            const float4 wv = wr[o4];             /* uniform -> s_load */     \
            acc[o4 * 4 + 0] = __fmaf_rn(xv, wv.x, acc[o4 * 4 + 0]);           \
            acc[o4 * 4 + 1] = __fmaf_rn(xv, wv.y, acc[o4 * 4 + 1]);           \
            acc[o4 * 4 + 2] = __fmaf_rn(xv, wv.z, acc[o4 * 4 + 2]);           \
            acc[o4 * 4 + 3] = __fmaf_rn(xv, wv.w, acc[o4 * 4 + 3]);           \
        }                                                                     \
    }

    #pragma unroll 1
    for (int half = 0; half < 2; ++half) {
        const int o0 = half * 32;
        float acc[32];
        #pragma unroll
        for (int o = 0; o < 32; ++o) acc[o] = 0.0f;

        float xa[16], xb[16];
        LOADX(xa, 0);                       // prologue
        #pragma unroll 1
        for (int kp = 0; kp < 3; ++kp) {    // 6 chunks, A/B two-step pipeline
            LOADX(xb, 2 * kp + 1);          // issue-early: next chunk in flight
            COMPUTE(xa, 2 * kp);            //   ...hidden under 1024cyc of FMA
            if (kp < 2) LOADX(xa, 2 * kp + 2);
            COMPUTE(xb, 2 * kp + 1);
        }

        #pragma unroll
        for (int o4 = 0; o4 < 8; ++o4) {    // bias + coalesced store
            float4 v;
            v.x = __fadd_rn(acc[o4 * 4 + 0], b1[o0 + o4 * 4 + 0]);
            v.y = __fadd_rn(acc[o4 * 4 + 1], b1[o0 + o4 * 4 + 1]);
            v.z = __fadd_rn(acc[o4 * 4 + 2], b1[o0 + o4 * 4 + 2]);
            v.w = __fadd_rn(acc[o4 * 4 + 3], b1[o0 + o4 * 4 + 3]);
            reinterpret_cast<float4*>(dst + o0)[o4] = v;
        }
    }
#undef LOADX
#undef COMPUTE
}

// ---------------- K2: layer-1 recurrence (in-place cur1 -> spk) ----------------
__global__ __launch_bounds__(64) void k2_rec1(float* cs)  // outs region
{
    const int b = blockIdx.x;
    const int h = threadIdx.x;
    const size_t str  = (size_t)BATCH * N_HID;
    const size_t base = (size_t)b * N_HID + h;

    float A[CH], Bv[CH];
    #pragma unroll
    for (int i = 0; i < CH; ++i) A[i] = cs[(size_t)i * str + base];

    float mem = 0.f, s = 0.f;
    for (int cp = 0; cp < 5; ++cp) {            // 10 chunks, processed in pairs
        const int c0 = 2 * cp;
        #pragma unroll
        for (int i = 0; i < CH; ++i)            // prefetch chunk c0+1
            Bv[i] = cs[(size_t)((c0 + 1) * CH + i) * str + base];
        #pragma unroll
        for (int i = 0; i < CH; ++i) {          // compute chunk c0 from A
            const float m = __fsub_rn(__fadd_rn(__fmul_rn(0.95f, mem), A[i]), s);
            mem = m; s = (m > 1.0f) ? 1.0f : 0.0f;
            cs[(size_t)(c0 * CH + i) * str + base] = s;
        }
        if (cp < 4) {
            #pragma unroll
            for (int i = 0; i < CH; ++i)        // prefetch chunk c0+2
                A[i] = cs[(size_t)((c0 + 2) * CH + i) * str + base];
        }
        #pragma unroll
        for (int i = 0; i < CH; ++i) {          // compute chunk c0+1 from Bv
            const float m = __fsub_rn(__fadd_rn(__fmul_rn(0.95f, mem), Bv[i]), s);
            mem = m; s = (m > 1.0f) ? 1.0f : 0.0f;
            cs[(size_t)((c0 + 1) * CH + i) * str + base] = s;
        }
    }
}

// ---------------- K3: cur2 = spk @ W2 + b2 ----------------
// grid 256*8, block 64. Each block: one b, one 64-t tile (last tile 52).
__global__ __launch_bounds__(64) void k3_cur2(
    const float* __restrict__ spk,  // (T,B,64) in outs
    const float* __restrict__ W2,   // (64,80)
    const float* __restrict__ b2,   // (80)
    float* __restrict__ cur2)       // (T,B,80) = outm region
{
    const int b    = blockIdx.x >> 3;
    const int tc   = blockIdx.x & 7;
    const int lane = threadIdx.x;           // = t within tile
    const int t    = tc * 64 + lane;        // 0..511
    const int tt   = (t < T_STEPS) ? t : (T_STEPS - 1);  // clamp loads

    const float* __restrict__ sp = spk + ((size_t)tt * BATCH + b) * N_HID;

    #pragma unroll 1
    for (int half = 0; half < 2; ++half) {
        const int o0 = half * 40;
        float acc[40];
        #pragma unroll
        for (int o = 0; o < 40; ++o) acc[o] = 0.0f;

        #pragma unroll 1                   // spk chunks strictly sequential
        for (int hc = 0; hc < 4; ++hc) {
            float sr[16];                  // per-lane spk chunk (16 VGPR)
            const float4* __restrict__ sp4 =
                reinterpret_cast<const float4*>(sp + hc * 16);
            #pragma unroll
            for (int q = 0; q < 4; ++q) {
                const float4 v = sp4[q];   // per-lane, 64B line per lane (L1)
                sr[q * 4 + 0] = v.x; sr[q * 4 + 1] = v.y;
                sr[q * 4 + 2] = v.z; sr[q * 4 + 3] = v.w;
            }
            #pragma unroll
            for (int j = 0; j < 16; ++j) { // ascending-h single-acc chains
                const int hh = hc * 16 + j;
                const float4* __restrict__ wr =
                    reinterpret_cast<const float4*>(W2 + (size_t)hh * N_OUT + o0);
                const float sv = sr[j];
                #pragma unroll
                for (int o4 = 0; o4 < 10; ++o4) {
                    const float4 wv = wr[o4];  // wave-uniform -> s_load
                    acc[o4 * 4 + 0] = __fmaf_rn(sv, wv.x, acc[o4 * 4 + 0]);
                    acc[o4 * 4 + 1] = __fmaf_rn(sv, wv.y, acc[o4 * 4 + 1]);
                    acc[o4 * 4 + 2] = __fmaf_rn(sv, wv.z, acc[o4 * 4 + 2]);
                    acc[o4 * 4 + 3] = __fmaf_rn(sv, wv.w, acc[o4 * 4 + 3]);
                }
            }
        }

        if (t < T_STEPS) {
            float* dst = cur2 + ((size_t)t * BATCH + b) * N_OUT + o0;
            #pragma unroll
            for (int o4 = 0; o4 < 10; ++o4) {
                float4 v;
                v.x = __fadd_rn(acc[o4 * 4 + 0], b2[o0 + o4 * 4 + 0]);
                v.y = __fadd_rn(acc[o4 * 4 + 1], b2[o0 + o4 * 4 + 1]);
                v.z = __fadd_rn(acc[o4 * 4 + 2], b2[o0 + o4 * 4 + 2]);
                v.w = __fadd_rn(acc[o4 * 4 + 3], b2[o0 + o4 * 4 + 3]);
                reinterpret_cast<float4*>(dst)[o4] = v;
            }
        }
    }
}

// ---------------- K4: layer-2 recurrence (cur2 in outm -> spk/mem finals) ----------------
__global__ __launch_bounds__(80) void k4_rec2(float* cm, float* os)
{
    const int b = blockIdx.x;
    const int o = threadIdx.x;   // 0..79
    const size_t str  = (size_t)BATCH * N_OUT;
    const size_t base = (size_t)b * N_OUT + o;

    float A[CH], Bv[CH];
    #pragma unroll
    for (int i = 0; i < CH; ++i) A[i] = cm[(size_t)i * str + base];

    float mem = 0.f, s = 0.f;
    for (int cp = 0; cp < 5; ++cp) {
        const int c0 = 2 * cp;
        #pragma unroll
        for (int i = 0; i < CH; ++i)
            Bv[i] = cm[(size_t)((c0 + 1) * CH + i) * str + base];
        #pragma unroll
        for (int i = 0; i < CH; ++i) {
            const int t = c0 * CH + i;
            const float m = __fsub_rn(__fadd_rn(__fmul_rn(0.95f, mem), A[i]), s);
            mem = m; s = (m > 1.0f) ? 1.0f : 0.0f;
            os[(size_t)t * str + base] = s;
            cm[(size_t)t * str + base] = m;
        }
        if (cp < 4) {
            #pragma unroll
            for (int i = 0; i < CH; ++i)
                A[i] = cm[(size_t)((c0 + 2) * CH + i) * str + base];
        }
        #pragma unroll
        for (int i = 0; i < CH; ++i) {
            const int t = (c0 + 1) * CH + i;
            const float m = __fsub_rn(__fadd_rn(__fmul_rn(0.95f, mem), Bv[i]), s);
            mem = m; s = (m > 1.0f) ? 1.0f : 0.0f;
            os[(size_t)t * str + base] = s;
            cm[(size_t)t * str + base] = m;
        }
    }
}

extern "C" void kernel_launch(void* const* d_in, const int* in_sizes, int n_in,
                              void* d_out, int out_size, void* d_ws, size_t ws_size,
                              hipStream_t stream) {
    const float* x  = (const float*)d_in[0];
    const float* W1 = (const float*)d_in[1];
    const float* b1 = (const float*)d_in[2];
    const float* W2 = (const float*)d_in[3];
    const float* b2 = (const float*)d_in[4];
    float* outs = (float*)d_out;                                   // (T,B,80) spikes
    float* outm = outs + (size_t)T_STEPS * BATCH * N_OUT;          // (T,B,80) mem

    k1_cur1<<<T_STEPS * 4, 64, 0, stream>>>(x, W1, b1, outs);      // cur1 -> outs
    k2_rec1<<<BATCH, 64, 0, stream>>>(outs);                       // spk overwrites cur1
    k3_cur2<<<BATCH * 8, 64, 0, stream>>>(outs, W2, b2, outm);     // cur2 -> outm
    k4_rec2<<<BATCH, 80, 0, stream>>>(outm, outs);                 // finals in place
}

// Round 7
// 160.447 us; speedup vs baseline: 1.0864x; 1.0864x over previous
//
#include <hip/hip_runtime.h>

// SNN classifier: T=500, B=256, 96 -> 64 -> 80, leaky (subtract reset).
// f32 BLAS-order arithmetic replicated exactly (single-accumulator
// k-ascending __fmaf_rn chains; fixed leaky op-sequence) -> outputs
// bitwise-identical to the passing round-2..6 kernels.
//
// Round-7: round-6 K1 (124us, VALUBusy 21%) stalled on the scalar W1
// stream: 1:4 s_load:FMA ratio, no deep pipelining on the scalar path,
// 2 waves/SIMD. Fix = GEMM register tiling: per-lane 2t x 16o tile means
// one 64B-contiguous uniform W1 slice (s_load_dwordx16-able) feeds 32
// FMAs (1:32), and the grid splits into 4 o-quarters -> 4000 waves
// (~3.9/SIMD, 2x occupancy). x stays per-lane VMEM, A/B double-buffered,
// statically indexed. Chain order per output unchanged.
// K2/K3/K4 untouched.

#define T_STEPS 500
#define BATCH   256
#define N_IN    96
#define N_HID   64
#define N_OUT   80
#define CH      50   // chunk size in K2/K4 (500 = 10*50)

// ---------------- K1: cur1 = x @ W1 + b1 ----------------
// grid 250*16, block 64. Block = (t-pair, 64-b group, 16-o quarter). Lane=b.
__global__ __launch_bounds__(64) void k1_cur1(
    const float* __restrict__ x,   // (T,B,96)
    const float* __restrict__ W1,  // (96,64)
    const float* __restrict__ b1,  // (64)
    float* __restrict__ cur1)      // (T,B,64) region inside outs
{
    const int tp = blockIdx.x >> 4;          // 0..249
    const int bg = (blockIdx.x >> 2) & 3;    // 0..3
    const int oq = blockIdx.x & 3;           // 0..3
    const int t0 = tp * 2;
    const int b  = (bg << 6) + threadIdx.x;
    const int o0 = oq << 4;

    const float* __restrict__ xr0 = x + ((size_t)t0 * BATCH + b) * N_IN;
    const float* __restrict__ xr1 = xr0 + (size_t)BATCH * N_IN;

    float acc0[16], acc1[16];
    #pragma unroll
    for (int o = 0; o < 16; ++o) { acc0[o] = 0.0f; acc1[o] = 0.0f; }

#define LOADX(buf, ptr, kc)                                                   \
    {                                                                         \
        const float4* __restrict__ p =                                        \
            reinterpret_cast<const float4*>((ptr) + (kc) * 16);               \
        float4 v0 = p[0], v1 = p[1], v2 = p[2], v3 = p[3];                    \
        buf[0]=v0.x;  buf[1]=v0.y;  buf[2]=v0.z;  buf[3]=v0.w;                \
        buf[4]=v1.x;  buf[5]=v1.y;  buf[6]=v1.z;  buf[7]=v1.w;                \
        buf[8]=v2.x;  buf[9]=v2.y;  buf[10]=v2.z; buf[11]=v2.w;               \
        buf[12]=v3.x; buf[13]=v3.y; buf[14]=v3.z; buf[15]=v3.w;               \
    }

// per k: one 64B wave-uniform W1 slice (16 floats) feeds 2t x 16o = 32 FMAs
#define COMPUTE(bufa, bufb, kc)                                               \
    _Pragma("unroll")                                                         \
    for (int j = 0; j < 16; ++j) {                                            \
        const float4* __restrict__ wr = reinterpret_cast<const float4*>(      \
            W1 + (size_t)((kc) * 16 + j) * N_HID + o0);                       \
        const float4 w0 = wr[0], w1 = wr[1], w2 = wr[2], w3 = wr[3];          \
        const float xv0 = bufa[j], xv1 = bufb[j];                             \
        acc0[0]  = __fmaf_rn(xv0, w0.x, acc0[0]);                             \
        acc0[1]  = __fmaf_rn(xv0, w0.y, acc0[1]);                             \
        acc0[2]  = __fmaf_rn(xv0, w0.z, acc0[2]);                             \
        acc0[3]  = __fmaf_rn(xv0, w0.w, acc0[3]);                             \
        acc0[4]  = __fmaf_rn(xv0, w1.x, acc0[4]);                             \
        acc0[5]  = __fmaf_rn(xv0, w1.y, acc0[5]);                             \
        acc0[6]  = __fmaf_rn(xv0, w1.z, acc0[6]);                             \
        acc0[7]  = __fmaf_rn(xv0, w1.w, acc0[7]);                             \
        acc0[8]  = __fmaf_rn(xv0, w2.x, acc0[8]);                             \
        acc0[9]  = __fmaf_rn(xv0, w2.y, acc0[9]);                             \
        acc0[10] = __fmaf_rn(xv0, w2.z, acc0[10]);                            \
        acc0[11] = __fmaf_rn(xv0, w2.w, acc0[11]);                            \
        acc0[12] = __fmaf_rn(xv0, w3.x, acc0[12]);                            \
        acc0[13] = __fmaf_rn(xv0, w3.y, acc0[13]);                            \
        acc0[14] = __fmaf_rn(xv0, w3.z, acc0[14]);                            \
        acc0[15] = __fmaf_rn(xv0, w3.w, acc0[15]);                            \
        acc1[0]  = __fmaf_rn(xv1, w0.x, acc1[0]);                             \
        acc1[1]  = __fmaf_rn(xv1, w0.y, acc1[1]);                             \
        acc1[2]  = __fmaf_rn(xv1, w0.z, acc1[2]);                             \
        acc1[3]  = __fmaf_rn(xv1, w0.w, acc1[3]);                             \
        acc1[4]  = __fmaf_rn(xv1, w1.x, acc1[4]);                             \
        acc1[5]  = __fmaf_rn(xv1, w1.y, acc1[5]);                             \
        acc1[6]  = __fmaf_rn(xv1, w1.z, acc1[6]);                             \
        acc1[7]  = __fmaf_rn(xv1, w1.w, acc1[7]);                             \
        acc1[8]  = __fmaf_rn(xv1, w2.x, acc1[8]);                             \
        acc1[9]  = __fmaf_rn(xv1, w2.y, acc1[9]);                             \
        acc1[10] = __fmaf_rn(xv1, w2.z, acc1[10]);                            \
        acc1[11] = __fmaf_rn(xv1, w2.w, acc1[11]);                            \
        acc1[12] = __fmaf_rn(xv1, w3.x, acc1[12]);                            \
        acc1[13] = __fmaf_rn(xv1, w3.y, acc1[13]);                            \
        acc1[14] = __fmaf_rn(xv1, w3.z, acc1[14]);                            \
        acc1[15] = __fmaf_rn(xv1, w3.w, acc1[15]);                            \
    }

    float xa0[16], xa1[16], xb0[16], xb1[16];
    LOADX(xa0, xr0, 0); LOADX(xa1, xr1, 0);        // prologue

    #pragma unroll 1
    for (int kp = 0; kp < 3; ++kp) {               // chunk pairs (2kp, 2kp+1)
        LOADX(xb0, xr0, 2 * kp + 1);               // issue-early next chunk
        LOADX(xb1, xr1, 2 * kp + 1);
        COMPUTE(xa0, xa1, 2 * kp);                 // 1024 cyc of FMA cover
        if (kp < 2) { LOADX(xa0, xr0, 2 * kp + 2); LOADX(xa1, xr1, 2 * kp + 2); }
        COMPUTE(xb0, xb1, 2 * kp + 1);
    }

    // bias + stores (4 float4 per t-row)
    float* dst0 = cur1 + ((size_t)t0 * BATCH + b) * N_HID + o0;
    float* dst1 = dst0 + (size_t)BATCH * N_HID;
    #pragma unroll
    for (int o4 = 0; o4 < 4; ++o4) {
        float4 v0, v1;
        v0.x = __fadd_rn(acc0[o4 * 4 + 0], b1[o0 + o4 * 4 + 0]);
        v0.y = __fadd_rn(acc0[o4 * 4 + 1], b1[o0 + o4 * 4 + 1]);
        v0.z = __fadd_rn(acc0[o4 * 4 + 2], b1[o0 + o4 * 4 + 2]);
        v0.w = __fadd_rn(acc0[o4 * 4 + 3], b1[o0 + o4 * 4 + 3]);
        v1.x = __fadd_rn(acc1[o4 * 4 + 0], b1[o0 + o4 * 4 + 0]);
        v1.y = __fadd_rn(acc1[o4 * 4 + 1], b1[o0 + o4 * 4 + 1]);
        v1.z = __fadd_rn(acc1[o4 * 4 + 2], b1[o0 + o4 * 4 + 2]);
        v1.w = __fadd_rn(acc1[o4 * 4 + 3], b1[o0 + o4 * 4 + 3]);
        reinterpret_cast<float4*>(dst0)[o4] = v0;
        reinterpret_cast<float4*>(dst1)[o4] = v1;
    }
#undef LOADX
#undef COMPUTE
}

// ---------------- K2: layer-1 recurrence (in-place cur1 -> spk) ----------------
__global__ __launch_bounds__(64) void k2_rec1(float* cs)  // outs region
{
    const int b = blockIdx.x;
    const int h = threadIdx.x;
    const size_t str  = (size_t)BATCH * N_HID;
    const size_t base = (size_t)b * N_HID + h;

    float A[CH], Bv[CH];
    #pragma unroll
    for (int i = 0; i < CH; ++i) A[i] = cs[(size_t)i * str + base];

    float mem = 0.f, s = 0.f;
    for (int cp = 0; cp < 5; ++cp) {            // 10 chunks, processed in pairs
        const int c0 = 2 * cp;
        #pragma unroll
        for (int i = 0; i < CH; ++i)            // prefetch chunk c0+1
            Bv[i] = cs[(size_t)((c0 + 1) * CH + i) * str + base];
        #pragma unroll
        for (int i = 0; i < CH; ++i) {          // compute chunk c0 from A
            const float m = __fsub_rn(__fadd_rn(__fmul_rn(0.95f, mem), A[i]), s);
            mem = m; s = (m > 1.0f) ? 1.0f : 0.0f;
            cs[(size_t)(c0 * CH + i) * str + base] = s;
        }
        if (cp < 4) {
            #pragma unroll
            for (int i = 0; i < CH; ++i)        // prefetch chunk c0+2
                A[i] = cs[(size_t)((c0 + 2) * CH + i) * str + base];
        }
        #pragma unroll
        for (int i = 0; i < CH; ++i) {          // compute chunk c0+1 from Bv
            const float m = __fsub_rn(__fadd_rn(__fmul_rn(0.95f, mem), Bv[i]), s);
            mem = m; s = (m > 1.0f) ? 1.0f : 0.0f;
            cs[(size_t)((c0 + 1) * CH + i) * str + base] = s;
        }
    }
}

// ---------------- K3: cur2 = spk @ W2 + b2 ----------------
// grid 256*8, block 64. Each block: one b, one 64-t tile (last tile 52).
__global__ __launch_bounds__(64) void k3_cur2(
    const float* __restrict__ spk,  // (T,B,64) in outs
    const float* __restrict__ W2,   // (64,80)
    const float* __restrict__ b2,   // (80)
    float* __restrict__ cur2)       // (T,B,80) = outm region
{
    const int b    = blockIdx.x >> 3;
    const int tc   = blockIdx.x & 7;
    const int lane = threadIdx.x;           // = t within tile
    const int t    = tc * 64 + lane;        // 0..511
    const int tt   = (t < T_STEPS) ? t : (T_STEPS - 1);  // clamp loads

    const float* __restrict__ sp = spk + ((size_t)tt * BATCH + b) * N_HID;

    #pragma unroll 1
    for (int half = 0; half < 2; ++half) {
        const int o0 = half * 40;
        float acc[40];
        #pragma unroll
        for (int o = 0; o < 40; ++o) acc[o] = 0.0f;

        #pragma unroll 1                   // spk chunks strictly sequential
        for (int hc = 0; hc < 4; ++hc) {
            float sr[16];                  // per-lane spk chunk (16 VGPR)
            const float4* __restrict__ sp4 =
                reinterpret_cast<const float4*>(sp + hc * 16);
            #pragma unroll
            for (int q = 0; q < 4; ++q) {
                const float4 v = sp4[q];   // per-lane, 64B line per lane (L1)
                sr[q * 4 + 0] = v.x; sr[q * 4 + 1] = v.y;
                sr[q * 4 + 2] = v.z; sr[q * 4 + 3] = v.w;
            }
            #pragma unroll
            for (int j = 0; j < 16; ++j) { // ascending-h single-acc chains
                const int hh = hc * 16 + j;
                const float4* __restrict__ wr =
                    reinterpret_cast<const float4*>(W2 + (size_t)hh * N_OUT + o0);
                const float sv = sr[j];
                #pragma unroll
                for (int o4 = 0; o4 < 10; ++o4) {
                    const float4 wv = wr[o4];  // wave-uniform -> s_load
                    acc[o4 * 4 + 0] = __fmaf_rn(sv, wv.x, acc[o4 * 4 + 0]);
                    acc[o4 * 4 + 1] = __fmaf_rn(sv, wv.y, acc[o4 * 4 + 1]);
                    acc[o4 * 4 + 2] = __fmaf_rn(sv, wv.z, acc[o4 * 4 + 2]);
                    acc[o4 * 4 + 3] = __fmaf_rn(sv, wv.w, acc[o4 * 4 + 3]);
                }
            }
        }

        if (t < T_STEPS) {
            float* dst = cur2 + ((size_t)t * BATCH + b) * N_OUT + o0;
            #pragma unroll
            for (int o4 = 0; o4 < 10; ++o4) {
                float4 v;
                v.x = __fadd_rn(acc[o4 * 4 + 0], b2[o0 + o4 * 4 + 0]);
                v.y = __fadd_rn(acc[o4 * 4 + 1], b2[o0 + o4 * 4 + 1]);
                v.z = __fadd_rn(acc[o4 * 4 + 2], b2[o0 + o4 * 4 + 2]);
                v.w = __fadd_rn(acc[o4 * 4 + 3], b2[o0 + o4 * 4 + 3]);
                reinterpret_cast<float4*>(dst)[o4] = v;
            }
        }
    }
}

// ---------------- K4: layer-2 recurrence (cur2 in outm -> spk/mem finals) ----------------
__global__ __launch_bounds__(80) void k4_rec2(float* cm, float* os)
{
    const int b = blockIdx.x;
    const int o = threadIdx.x;   // 0..79
    const size_t str  = (size_t)BATCH * N_OUT;
    const size_t base = (size_t)b * N_OUT + o;

    float A[CH], Bv[CH];
    #pragma unroll
    for (int i = 0; i < CH; ++i) A[i] = cm[(size_t)i * str + base];

    float mem = 0.f, s = 0.f;
    for (int cp = 0; cp < 5; ++cp) {
        const int c0 = 2 * cp;
        #pragma unroll
        for (int i = 0; i < CH; ++i)
            Bv[i] = cm[(size_t)((c0 + 1) * CH + i) * str + base];
        #pragma unroll
        for (int i = 0; i < CH; ++i) {
            const int t = c0 * CH + i;
            const float m = __fsub_rn(__fadd_rn(__fmul_rn(0.95f, mem), A[i]), s);
            mem = m; s = (m > 1.0f) ? 1.0f : 0.0f;
            os[(size_t)t * str + base] = s;
            cm[(size_t)t * str + base] = m;
        }
        if (cp < 4) {
            #pragma unroll
            for (int i = 0; i < CH; ++i)
                A[i] = cm[(size_t)((c0 + 2) * CH + i) * str + base];
        }
        #pragma unroll
        for (int i = 0; i < CH; ++i) {
            const int t = (c0 + 1) * CH + i;
            const float m = __fsub_rn(__fadd_rn(__fmul_rn(0.95f, mem), Bv[i]), s);
            mem = m; s = (m > 1.0f) ? 1.0f : 0.0f;
            os[(size_t)t * str + base] = s;
            cm[(size_t)t * str + base] = m;
        }
    }
}

extern "C" void kernel_launch(void* const* d_in, const int* in_sizes, int n_in,
                              void* d_out, int out_size, void* d_ws, size_t ws_size,
                              hipStream_t stream) {
    const float* x  = (const float*)d_in[0];
    const float* W1 = (const float*)d_in[1];
    const float* b1 = (const float*)d_in[2];
    const float* W2 = (const float*)d_in[3];
    const float* b2 = (const float*)d_in[4];
    float* outs = (float*)d_out;                                   // (T,B,80) spikes
    float* outm = outs + (size_t)T_STEPS * BATCH * N_OUT;          // (T,B,80) mem

    k1_cur1<<<250 * 16, 64, 0, stream>>>(x, W1, b1, outs);         // cur1 -> outs
    k2_rec1<<<BATCH, 64, 0, stream>>>(outs);                       // spk overwrites cur1
    k3_cur2<<<BATCH * 8, 64, 0, stream>>>(outs, W2, b2, outm);     // cur2 -> outm
    k4_rec2<<<BATCH, 80, 0, stream>>>(outm, outs);                 // finals in place
}

// Round 8
// 149.537 us; speedup vs baseline: 1.1657x; 1.0730x over previous
//
#include <hip/hip_runtime.h>

// SNN classifier: T=500, B=256, 96 -> 64 -> 80, leaky (subtract reset).
// f32 BLAS-order arithmetic replicated exactly (single-accumulator
// k-ascending __fmaf_rn chains; fixed leaky op-sequence) -> outputs
// bitwise-identical to the passing round-2..7 kernels.
//
// Round-8 (single-variable change vs round-7): K1's remaining stall is
// W1 scalar-fetch latency from scalar-L1 thrashing. With oq in the LOW
// blockIdx bits, each CU concurrently hosts all 4 o-quarters -> 24KB W1
// working set > 16KB sL1 -> every per-j s_load goes to L2 (~200cyc),
// exposed (only 64cyc FMA per j). Fix: oq = blockIdx HIGH bits -> the
// device runs o-quarters in temporal phases; during a phase each CU uses
// one 6KB W1 slice (sL1-resident, ~30cyc). The 4x logical x re-read
// across phases is L3-served (49MB << 256MB). Consecutive blocks now
// share the same t-pair -> contiguous x regions, better L2 locality.
// K2/K3/K4 untouched.

#define T_STEPS 500
#define BATCH   256
#define N_IN    96
#define N_HID   64
#define N_OUT   80
#define CH      50   // chunk size in K2/K4 (500 = 10*50)

// ---------------- K1: cur1 = x @ W1 + b1 ----------------
// grid 250*16, block 64. oq = blockIdx/1000 (phase), then tp, bg. Lane=b.
__global__ __launch_bounds__(64) void k1_cur1(
    const float* __restrict__ x,   // (T,B,96)
    const float* __restrict__ W1,  // (96,64)
    const float* __restrict__ b1,  // (64)
    float* __restrict__ cur1)      // (T,B,64) region inside outs
{
    const int oq  = blockIdx.x / 1000;       // 0..3  (HIGH bits -> phases)
    const int rem = blockIdx.x % 1000;
    const int tp  = rem >> 2;                // 0..249
    const int bg  = rem & 3;                 // 0..3
    const int t0 = tp * 2;
    const int b  = (bg << 6) + threadIdx.x;
    const int o0 = oq << 4;

    const float* __restrict__ xr0 = x + ((size_t)t0 * BATCH + b) * N_IN;
    const float* __restrict__ xr1 = xr0 + (size_t)BATCH * N_IN;

    float acc0[16], acc1[16];
    #pragma unroll
    for (int o = 0; o < 16; ++o) { acc0[o] = 0.0f; acc1[o] = 0.0f; }

#define LOADX(buf, ptr, kc)                                                   \
    {                                                                         \
        const float4* __restrict__ p =                                        \
            reinterpret_cast<const float4*>((ptr) + (kc) * 16);               \
        float4 v0 = p[0], v1 = p[1], v2 = p[2], v3 = p[3];                    \
        buf[0]=v0.x;  buf[1]=v0.y;  buf[2]=v0.z;  buf[3]=v0.w;                \
        buf[4]=v1.x;  buf[5]=v1.y;  buf[6]=v1.z;  buf[7]=v1.w;                \
        buf[8]=v2.x;  buf[9]=v2.y;  buf[10]=v2.z; buf[11]=v2.w;               \
        buf[12]=v3.x; buf[13]=v3.y; buf[14]=v3.z; buf[15]=v3.w;               \
    }

// per k: one 64B wave-uniform W1 slice (16 floats) feeds 2t x 16o = 32 FMAs
#define COMPUTE(bufa, bufb, kc)                                               \
    _Pragma("unroll")                                                         \
    for (int j = 0; j < 16; ++j) {                                            \
        const float4* __restrict__ wr = reinterpret_cast<const float4*>(      \
            W1 + (size_t)((kc) * 16 + j) * N_HID + o0);                       \
        const float4 w0 = wr[0], w1 = wr[1], w2 = wr[2], w3 = wr[3];          \
        const float xv0 = bufa[j], xv1 = bufb[j];                             \
        acc0[0]  = __fmaf_rn(xv0, w0.x, acc0[0]);                             \
        acc0[1]  = __fmaf_rn(xv0, w0.y, acc0[1]);                             \
        acc0[2]  = __fmaf_rn(xv0, w0.z, acc0[2]);                             \
        acc0[3]  = __fmaf_rn(xv0, w0.w, acc0[3]);                             \
        acc0[4]  = __fmaf_rn(xv0, w1.x, acc0[4]);                             \
        acc0[5]  = __fmaf_rn(xv0, w1.y, acc0[5]);                             \
        acc0[6]  = __fmaf_rn(xv0, w1.z, acc0[6]);                             \
        acc0[7]  = __fmaf_rn(xv0, w1.w, acc0[7]);                             \
        acc0[8]  = __fmaf_rn(xv0, w2.x, acc0[8]);                             \
        acc0[9]  = __fmaf_rn(xv0, w2.y, acc0[9]);                             \
        acc0[10] = __fmaf_rn(xv0, w2.z, acc0[10]);                            \
        acc0[11] = __fmaf_rn(xv0, w2.w, acc0[11]);                            \
        acc0[12] = __fmaf_rn(xv0, w3.x, acc0[12]);                            \
        acc0[13] = __fmaf_rn(xv0, w3.y, acc0[13]);                            \
        acc0[14] = __fmaf_rn(xv0, w3.z, acc0[14]);                            \
        acc0[15] = __fmaf_rn(xv0, w3.w, acc0[15]);                            \
        acc1[0]  = __fmaf_rn(xv1, w0.x, acc1[0]);                             \
        acc1[1]  = __fmaf_rn(xv1, w0.y, acc1[1]);                             \
        acc1[2]  = __fmaf_rn(xv1, w0.z, acc1[2]);                             \
        acc1[3]  = __fmaf_rn(xv1, w0.w, acc1[3]);                             \
        acc1[4]  = __fmaf_rn(xv1, w1.x, acc1[4]);                             \
        acc1[5]  = __fmaf_rn(xv1, w1.y, acc1[5]);                             \
        acc1[6]  = __fmaf_rn(xv1, w1.z, acc1[6]);                             \
        acc1[7]  = __fmaf_rn(xv1, w1.w, acc1[7]);                             \
        acc1[8]  = __fmaf_rn(xv1, w2.x, acc1[8]);                             \
        acc1[9]  = __fmaf_rn(xv1, w2.y, acc1[9]);                             \
        acc1[10] = __fmaf_rn(xv1, w2.z, acc1[10]);                            \
        acc1[11] = __fmaf_rn(xv1, w2.w, acc1[11]);                            \
        acc1[12] = __fmaf_rn(xv1, w3.x, acc1[12]);                            \
        acc1[13] = __fmaf_rn(xv1, w3.y, acc1[13]);                            \
        acc1[14] = __fmaf_rn(xv1, w3.z, acc1[14]);                            \
        acc1[15] = __fmaf_rn(xv1, w3.w, acc1[15]);                            \
    }

    float xa0[16], xa1[16], xb0[16], xb1[16];
    LOADX(xa0, xr0, 0); LOADX(xa1, xr1, 0);        // prologue

    #pragma unroll 1
    for (int kp = 0; kp < 3; ++kp) {               // chunk pairs (2kp, 2kp+1)
        LOADX(xb0, xr0, 2 * kp + 1);               // issue-early next chunk
        LOADX(xb1, xr1, 2 * kp + 1);
        COMPUTE(xa0, xa1, 2 * kp);                 // 1024 cyc of FMA cover
        if (kp < 2) { LOADX(xa0, xr0, 2 * kp + 2); LOADX(xa1, xr1, 2 * kp + 2); }
        COMPUTE(xb0, xb1, 2 * kp + 1);
    }

    // bias + stores (4 float4 per t-row)
    float* dst0 = cur1 + ((size_t)t0 * BATCH + b) * N_HID + o0;
    float* dst1 = dst0 + (size_t)BATCH * N_HID;
    #pragma unroll
    for (int o4 = 0; o4 < 4; ++o4) {
        float4 v0, v1;
        v0.x = __fadd_rn(acc0[o4 * 4 + 0], b1[o0 + o4 * 4 + 0]);
        v0.y = __fadd_rn(acc0[o4 * 4 + 1], b1[o0 + o4 * 4 + 1]);
        v0.z = __fadd_rn(acc0[o4 * 4 + 2], b1[o0 + o4 * 4 + 2]);
        v0.w = __fadd_rn(acc0[o4 * 4 + 3], b1[o0 + o4 * 4 + 3]);
        v1.x = __fadd_rn(acc1[o4 * 4 + 0], b1[o0 + o4 * 4 + 0]);
        v1.y = __fadd_rn(acc1[o4 * 4 + 1], b1[o0 + o4 * 4 + 1]);
        v1.z = __fadd_rn(acc1[o4 * 4 + 2], b1[o0 + o4 * 4 + 2]);
        v1.w = __fadd_rn(acc1[o4 * 4 + 3], b1[o0 + o4 * 4 + 3]);
        reinterpret_cast<float4*>(dst0)[o4] = v0;
        reinterpret_cast<float4*>(dst1)[o4] = v1;
    }
#undef LOADX
#undef COMPUTE
}

// ---------------- K2: layer-1 recurrence (in-place cur1 -> spk) ----------------
__global__ __launch_bounds__(64) void k2_rec1(float* cs)  // outs region
{
    const int b = blockIdx.x;
    const int h = threadIdx.x;
    const size_t str  = (size_t)BATCH * N_HID;
    const size_t base = (size_t)b * N_HID + h;

    float A[CH], Bv[CH];
    #pragma unroll
    for (int i = 0; i < CH; ++i) A[i] = cs[(size_t)i * str + base];

    float mem = 0.f, s = 0.f;
    for (int cp = 0; cp < 5; ++cp) {            // 10 chunks, processed in pairs
        const int c0 = 2 * cp;
        #pragma unroll
        for (int i = 0; i < CH; ++i)            // prefetch chunk c0+1
            Bv[i] = cs[(size_t)((c0 + 1) * CH + i) * str + base];
        #pragma unroll
        for (int i = 0; i < CH; ++i) {          // compute chunk c0 from A
            const float m = __fsub_rn(__fadd_rn(__fmul_rn(0.95f, mem), A[i]), s);
            mem = m; s = (m > 1.0f) ? 1.0f : 0.0f;
            cs[(size_t)(c0 * CH + i) * str + base] = s;
        }
        if (cp < 4) {
            #pragma unroll
            for (int i = 0; i < CH; ++i)        // prefetch chunk c0+2
                A[i] = cs[(size_t)((c0 + 2) * CH + i) * str + base];
        }
        #pragma unroll
        for (int i = 0; i < CH; ++i) {          // compute chunk c0+1 from Bv
            const float m = __fsub_rn(__fadd_rn(__fmul_rn(0.95f, mem), Bv[i]), s);
            mem = m; s = (m > 1.0f) ? 1.0f : 0.0f;
            cs[(size_t)((c0 + 1) * CH + i) * str + base] = s;
        }
    }
}

// ---------------- K3: cur2 = spk @ W2 + b2 ----------------
// grid 256*8, block 64. Each block: one b, one 64-t tile (last tile 52).
__global__ __launch_bounds__(64) void k3_cur2(
    const float* __restrict__ spk,  // (T,B,64) in outs
    const float* __restrict__ W2,   // (64,80)
    const float* __restrict__ b2,   // (80)
    float* __restrict__ cur2)       // (T,B,80) = outm region
{
    const int b    = blockIdx.x >> 3;
    const int tc   = blockIdx.x & 7;
    const int lane = threadIdx.x;           // = t within tile
    const int t    = tc * 64 + lane;        // 0..511
    const int tt   = (t < T_STEPS) ? t : (T_STEPS - 1);  // clamp loads

    const float* __restrict__ sp = spk + ((size_t)tt * BATCH + b) * N_HID;

    #pragma unroll 1
    for (int half = 0; half < 2; ++half) {
        const int o0 = half * 40;
        float acc[40];
        #pragma unroll
        for (int o = 0; o < 40; ++o) acc[o] = 0.0f;

        #pragma unroll 1                   // spk chunks strictly sequential
        for (int hc = 0; hc < 4; ++hc) {
            float sr[16];                  // per-lane spk chunk (16 VGPR)
            const float4* __restrict__ sp4 =
                reinterpret_cast<const float4*>(sp + hc * 16);
            #pragma unroll
            for (int q = 0; q < 4; ++q) {
                const float4 v = sp4[q];   // per-lane, 64B line per lane (L1)
                sr[q * 4 + 0] = v.x; sr[q * 4 + 1] = v.y;
                sr[q * 4 + 2] = v.z; sr[q * 4 + 3] = v.w;
            }
            #pragma unroll
            for (int j = 0; j < 16; ++j) { // ascending-h single-acc chains
                const int hh = hc * 16 + j;
                const float4* __restrict__ wr =
                    reinterpret_cast<const float4*>(W2 + (size_t)hh * N_OUT + o0);
                const float sv = sr[j];
                #pragma unroll
                for (int o4 = 0; o4 < 10; ++o4) {
                    const float4 wv = wr[o4];  // wave-uniform -> s_load
                    acc[o4 * 4 + 0] = __fmaf_rn(sv, wv.x, acc[o4 * 4 + 0]);
                    acc[o4 * 4 + 1] = __fmaf_rn(sv, wv.y, acc[o4 * 4 + 1]);
                    acc[o4 * 4 + 2] = __fmaf_rn(sv, wv.z, acc[o4 * 4 + 2]);
                    acc[o4 * 4 + 3] = __fmaf_rn(sv, wv.w, acc[o4 * 4 + 3]);
                }
            }
        }

        if (t < T_STEPS) {
            float* dst = cur2 + ((size_t)t * BATCH + b) * N_OUT + o0;
            #pragma unroll
            for (int o4 = 0; o4 < 10; ++o4) {
                float4 v;
                v.x = __fadd_rn(acc[o4 * 4 + 0], b2[o0 + o4 * 4 + 0]);
                v.y = __fadd_rn(acc[o4 * 4 + 1], b2[o0 + o4 * 4 + 1]);
                v.z = __fadd_rn(acc[o4 * 4 + 2], b2[o0 + o4 * 4 + 2]);
                v.w = __fadd_rn(acc[o4 * 4 + 3], b2[o0 + o4 * 4 + 3]);
                reinterpret_cast<float4*>(dst)[o4] = v;
            }
        }
    }
}

// ---------------- K4: layer-2 recurrence (cur2 in outm -> spk/mem finals) ----------------
__global__ __launch_bounds__(80) void k4_rec2(float* cm, float* os)
{
    const int b = blockIdx.x;
    const int o = threadIdx.x;   // 0..79
    const size_t str  = (size_t)BATCH * N_OUT;
    const size_t base = (size_t)b * N_OUT + o;

    float A[CH], Bv[CH];
    #pragma unroll
    for (int i = 0; i < CH; ++i) A[i] = cm[(size_t)i * str + base];

    float mem = 0.f, s = 0.f;
    for (int cp = 0; cp < 5; ++cp) {
        const int c0 = 2 * cp;
        #pragma unroll
        for (int i = 0; i < CH; ++i)
            Bv[i] = cm[(size_t)((c0 + 1) * CH + i) * str + base];
        #pragma unroll
        for (int i = 0; i < CH; ++i) {
            const int t = c0 * CH + i;
            const float m = __fsub_rn(__fadd_rn(__fmul_rn(0.95f, mem), A[i]), s);
            mem = m; s = (m > 1.0f) ? 1.0f : 0.0f;
            os[(size_t)t * str + base] = s;
            cm[(size_t)t * str + base] = m;
        }
        if (cp < 4) {
            #pragma unroll
            for (int i = 0; i < CH; ++i)
                A[i] = cm[(size_t)((c0 + 2) * CH + i) * str + base];
        }
        #pragma unroll
        for (int i = 0; i < CH; ++i) {
            const int t = (c0 + 1) * CH + i;
            const float m = __fsub_rn(__fadd_rn(__fmul_rn(0.95f, mem), Bv[i]), s);
            mem = m; s = (m > 1.0f) ? 1.0f : 0.0f;
            os[(size_t)t * str + base] = s;
            cm[(size_t)t * str + base] = m;
        }
    }
}

extern "C" void kernel_launch(void* const* d_in, const int* in_sizes, int n_in,
                              void* d_out, int out_size, void* d_ws, size_t ws_size,
                              hipStream_t stream) {
    const float* x  = (const float*)d_in[0];
    const float* W1 = (const float*)d_in[1];
    const float* b1 = (const float*)d_in[2];
    const float* W2 = (const float*)d_in[3];
    const float* b2 = (const float*)d_in[4];
    float* outs = (float*)d_out;                                   // (T,B,80) spikes
    float* outm = outs + (size_t)T_STEPS * BATCH * N_OUT;          // (T,B,80) mem

    k1_cur1<<<250 * 16, 64, 0, stream>>>(x, W1, b1, outs);         // cur1 -> outs
    k2_rec1<<<BATCH, 64, 0, stream>>>(outs);                       // spk overwrites cur1
    k3_cur2<<<BATCH * 8, 64, 0, stream>>>(outs, W2, b2, outm);     // cur2 -> outm
    k4_rec2<<<BATCH, 80, 0, stream>>>(outm, outs);                 // finals in place
}